// Round 9
// baseline (370.879 us; speedup 1.0000x reference)
//
#include <hip/hip_runtime.h>
#include <stdint.h>
#include <stddef.h>

// MultiHeadAttention B=4 S=2048 D=1024 H=16 E=64  (all fp32 in/out)
// R15: gemm_core 2-phase pipeline done right (R12's failure mode fixed):
//      4 NAMED shared buffers (As0/Bs0/As1/Bs1) -> compiler proves
//      stage(nxt) does not alias ds_read(cur), no spurious vmcnt waits;
//      FULL unroll of 16 K-steps -> (s&1) buffer select is compile-time,
//      k0*2B <= 1920 folds into the gld_lds 13-bit imm -> no per-step addr
//      VALU. STAGE(next) issued BEFORE compute(cur), ONE barrier/step ->
//      stage latency hides under 32 MFMA + 16 ds_read. LDS 32->64KB.
//      R14 proved swizzle works (conflicts 6.29M->0) but timing was
//      drain-bound (MfmaUtil 20.5, VALU 19.5, ~60% stall) - this attacks
//      the drain. Catalog m230: this structure at 128^2 = 682 TF (we: 505).
// R13/R14: BK=64 + chunk-XOR swizzle (conflict-free), XCD remap (FETCH 49MB).
// R10: manual RNE P-pack. R9: attn swizzle col fix. R8: attn KVBLK=64.
// R7: attn XCD swizzle. R6: S^T=MFMA(kf,qf). R5: fused QKV, Vtb transposed.

typedef __attribute__((ext_vector_type(8))) short short8;
typedef __attribute__((ext_vector_type(4))) float f32x4;

#if __has_builtin(__builtin_amdgcn_exp2f)
#define EXP2F __builtin_amdgcn_exp2f
#else
#define EXP2F exp2f
#endif
#if __has_builtin(__builtin_amdgcn_rcpf)
#define RCPF __builtin_amdgcn_rcpf
#else
#define RCPF(x) (1.0f / (x))
#endif

__device__ __forceinline__ uint16_t f2bf(float f) {
  uint32_t u = __builtin_bit_cast(uint32_t, f);
  u += 0x7FFFu + ((u >> 16) & 1u);  // RNE; inputs finite
  return (uint16_t)(u >> 16);
}

__device__ __forceinline__ void gld16(const void* g, void* l) {
  __builtin_amdgcn_global_load_lds((const __attribute__((address_space(1))) void*)g,
                                   (__attribute__((address_space(3))) void*)l, 16, 0, 0);
}

__global__ __launch_bounds__(256) void cast3(const float* __restrict__ s0, const float* __restrict__ s1,
                                             const float* __restrict__ s2, uint16_t* __restrict__ d0,
                                             uint16_t* __restrict__ d1, uint16_t* __restrict__ d2,
                                             int n4) {
  const int z = blockIdx.y;
  const float* s = z == 0 ? s0 : (z == 1 ? s1 : s2);
  uint16_t* d = z == 0 ? d0 : (z == 1 ? d1 : d2);
  int i = blockIdx.x * 256 + threadIdx.x;
  if (i >= n4) return;
  float4 v = ((const float4*)s)[i];
  ushort4 o;
  o.x = f2bf(v.x); o.y = f2bf(v.y); o.z = f2bf(v.z); o.w = f2bf(v.w);
  ((ushort4*)d)[i] = o;
}

__global__ __launch_bounds__(256) void cast4(const float* __restrict__ s0, const float* __restrict__ s1,
                                             const float* __restrict__ s2, const float* __restrict__ s3,
                                             uint16_t* __restrict__ d0, uint16_t* __restrict__ d1,
                                             uint16_t* __restrict__ d2, uint16_t* __restrict__ d3,
                                             int n4) {
  const int z = blockIdx.y;
  const float* s = z == 0 ? s0 : (z == 1 ? s1 : (z == 2 ? s2 : s3));
  uint16_t* d = z == 0 ? d0 : (z == 1 ? d1 : (z == 2 ? d2 : d3));
  int i = blockIdx.x * 256 + threadIdx.x;
  if (i >= n4) return;
  float4 v = ((const float4*)s)[i];
  ushort4 o;
  o.x = f2bf(v.x); o.y = f2bf(v.y); o.z = f2bf(v.z); o.w = f2bf(v.w);
  ((ushort4*)d)[i] = o;
}

// Stage one 128x64 tile pair (A,B) at k-offset k0 into the given buffers.
__device__ __forceinline__ void gemm_stage(const uint16_t* const* Ag, const uint16_t* const* Bg,
                                           const int* lofs, uint16_t* As, uint16_t* Bs, int k0) {
#pragma unroll
  for (int c = 0; c < 4; ++c) {
    gld16(Ag[c] + k0, As + lofs[c]);
    gld16(Bg[c] + k0, Bs + lofs[c]);
  }
}

// One 128x128 frag-step over the 64-wide K slice in As/Bs (swizzled).
__device__ __forceinline__ void gemm_compute(const uint16_t* As, const uint16_t* Bs,
                                             f32x4 acc[4][4], int wm, int wn, int ln, int quad,
                                             const int* colk) {
#pragma unroll
  for (int kk = 0; kk < 2; ++kk) {
    short8 a[4], b[4];
#pragma unroll
    for (int mt = 0; mt < 4; ++mt)
      a[mt] = *(const short8*)(As + (wm + mt * 16 + ln) * 64 + colk[kk] * 8);
#pragma unroll
    for (int nt = 0; nt < 4; ++nt)
      b[nt] = *(const short8*)(Bs + (wn + nt * 16 + ln) * 64 + colk[kk] * 8);
#pragma unroll
    for (int mt = 0; mt < 4; ++mt)
#pragma unroll
      for (int nt = 0; nt < 4; ++nt)
        acc[mt][nt] = __builtin_amdgcn_mfma_f32_16x16x32_bf16(a[mt], b[nt], acc[mt][nt], 0, 0, 0);
  }
}

// 128x128xK=1024 bf16 MFMA core, BK=64, chunk-XOR-swizzled LDS, 2-phase.
// LDS[row][cp] holds global chunk g=(cp-row)&7 (linear dest for gld_lds,
// pre-swizzled global src). Frag read k-slice g'=kk*4+quad at row
// (row&7==ln&7): cp=(g'+ln)&7. Per step s: STAGE(s+1 -> nxt buf) issued
// first, compute(cur buf), one barrier. Full unroll -> static buf select.
__device__ __forceinline__ void gemm_core(const uint16_t* __restrict__ A,
                                          const uint16_t* __restrict__ Bw,
                                          uint16_t* As0, uint16_t* Bs0,
                                          uint16_t* As1, uint16_t* Bs1,
                                          f32x4 acc[4][4], int m0, int n0) {
  constexpr int K = 1024;
  const int tid = threadIdx.x;
  const int w = tid >> 6, l = tid & 63;
  const int ln = l & 15, quad = l >> 4;
  const int wm = (w >> 1) * 64, wn = (w & 1) * 64;

  const uint16_t* Ag[4];
  const uint16_t* Bg[4];
  int lofs[4];
#pragma unroll
  for (int c = 0; c < 4; ++c) {
    const int f = c * 256 + tid;              // chunk id 0..1023
    const int row = f >> 3, cp = f & 7, g = (cp - row) & 7;
    Ag[c] = A + (size_t)(m0 + row) * K + g * 8;
    Bg[c] = Bw + (size_t)(n0 + row) * K + g * 8;
    lofs[c] = f * 8;                          // linear LDS dest (elems)
  }
  int colk[2];
#pragma unroll
  for (int kk = 0; kk < 2; ++kk) colk[kk] = (kk * 4 + quad + ln) & 7;

  gemm_stage(Ag, Bg, lofs, As0, Bs0, 0);
  __syncthreads();
#pragma unroll
  for (int s = 0; s < 16; ++s) {
    uint16_t* Asn = (s & 1) ? As0 : As1;      // static: s is compile-time
    uint16_t* Bsn = (s & 1) ? Bs0 : Bs1;
    const uint16_t* Asc = (s & 1) ? As1 : As0;
    const uint16_t* Bsc = (s & 1) ? Bs1 : Bs0;
    if (s < 15) gemm_stage(Ag, Bg, lofs, Asn, Bsn, (s + 1) * 64);
    gemm_compute(Asc, Bsc, acc, wm, wn, ln, quad, colk);
    if (s < 15) __syncthreads();  // drains stage (vmcnt0) + cur reads (lgkmcnt0)
  }
}

// Fused QKV projection: z selects tensor.
// z=0: Q -> [B,H,S,E] scaled; z=1: K -> [B,H,S,E]; z=2: V -> [B,H,E,S] (transposed).
// XCD remap: xcd = lin&7 owns contiguous (z,m)-chunk x all 8 n-tiles ->
// A-tile reused 8x inside one L2 (R12/R14 measured: FETCH 200->42-49MB).
__global__ __launch_bounds__(256) void gemm_qkv(const uint16_t* __restrict__ Xq, const uint16_t* __restrict__ Xk,
                                                const uint16_t* __restrict__ Xv, const uint16_t* __restrict__ Wq,
                                                const uint16_t* __restrict__ Wk, const uint16_t* __restrict__ Wv,
                                                const float* __restrict__ bq, const float* __restrict__ bk,
                                                const float* __restrict__ bv, uint16_t* __restrict__ Qb,
                                                uint16_t* __restrict__ Kb, uint16_t* __restrict__ Vtb,
                                                float qscale, int zbase) {
  __shared__ __attribute__((aligned(16))) uint16_t As0[128 * 64];
  __shared__ __attribute__((aligned(16))) uint16_t Bs0[128 * 64];
  __shared__ __attribute__((aligned(16))) uint16_t As1[128 * 64];
  __shared__ __attribute__((aligned(16))) uint16_t Bs1[128 * 64];
  // Bijective remap (nmz = 64*gridDim.z m/z-tiles, 8 n-tiles):
  const int lin = blockIdx.x + (blockIdx.y << 3) + (blockIdx.z << 9);
  const int per = gridDim.z << 3;                // mz-tiles per XCD
  const int xcd = lin & 7, local = lin >> 3;
  const int mz = xcd * per + (local >> 3);
  const int z = (mz >> 6) + zbase;
  const int m0 = (mz & 63) * 128, n0 = (local & 7) * 128;

  const uint16_t* A = z == 0 ? Xq : (z == 1 ? Xk : Xv);
  const uint16_t* Bw = z == 0 ? Wq : (z == 1 ? Wk : Wv);
  const float* bias = z == 0 ? bq : (z == 1 ? bk : bv);
  uint16_t* Cout = z == 0 ? Qb : (z == 1 ? Kb : Vtb);
  const float scale = z == 0 ? qscale : 1.0f;

  f32x4 acc[4][4] = {};
  gemm_core(A, Bw, As0, Bs0, As1, Bs1, acc, m0, n0);

  const int tid = threadIdx.x;
  const int w = tid >> 6, l = tid & 63;
  const int ln = l & 15, quad = l >> 4;
  const int wm = (w >> 1) * 64, wn = (w & 1) * 64;
#pragma unroll
  for (int nt = 0; nt < 4; ++nt) {
    const int col = n0 + wn + nt * 16 + ln;
    const float bv_ = bias[col];
    const int h = col >> 6, e = col & 63;
#pragma unroll
    for (int mt = 0; mt < 4; ++mt) {
#pragma unroll
      for (int i = 0; i < 4; ++i) {
        const int row = m0 + wm + mt * 16 + quad * 4 + i;
        const int b_ = row >> 11, s = row & 2047;
        const float v = (acc[mt][nt][i] + bv_) * scale;
        if (z != 2) {
          Cout[(size_t)(b_ * 16 + h) * 131072 + s * 64 + e] = f2bf(v);
        } else {
          Cout[(size_t)(b_ * 16 + h) * 131072 + e * 2048 + s] = f2bf(v);
        }
      }
    }
  }
}

// Output projection: fp32 row-major out. Same XCD remap (per=8).
__global__ __launch_bounds__(256) void gemm_out(const uint16_t* __restrict__ A, const uint16_t* __restrict__ Bw,
                                                const float* __restrict__ bias, float* __restrict__ Cout) {
  __shared__ __attribute__((aligned(16))) uint16_t As0[128 * 64];
  __shared__ __attribute__((aligned(16))) uint16_t Bs0[128 * 64];
  __shared__ __attribute__((aligned(16))) uint16_t As1[128 * 64];
  __shared__ __attribute__((aligned(16))) uint16_t Bs1[128 * 64];
  const int lin = blockIdx.x + (blockIdx.y << 3);
  const int xcd = lin & 7, local = lin >> 3;
  const int m0 = (xcd * 8 + (local >> 3)) * 128, n0 = (local & 7) * 128;
  f32x4 acc[4][4] = {};
  gemm_core(A, Bw, As0, Bs0, As1, Bs1, acc, m0, n0);

  const int tid = threadIdx.x;
  const int w = tid >> 6, l = tid & 63;
  const int ln = l & 15, quad = l >> 4;
  const int wm = (w >> 1) * 64, wn = (w & 1) * 64;
#pragma unroll
  for (int nt = 0; nt < 4; ++nt) {
    const int col = n0 + wn + nt * 16 + ln;
    const float bv_ = bias[col];
#pragma unroll
    for (int mt = 0; mt < 4; ++mt)
#pragma unroll
      for (int i = 0; i < 4; ++i) {
        const int row = m0 + wm + mt * 16 + quad * 4 + i;
        Cout[(size_t)row * 1024 + col] = acc[mt][nt][i] + bv_;
      }
  }
}

// One block = 128 query rows of one (b,h); wave = 32 rows (2 subtiles of 16).
// R10 attn (passing, unchanged): KVBLK=64 -> LDS 34.8KB -> 4 blocks/CU.
// K/V staged via global_load_lds with chunk XOR-swizzle: LDS[row][cp] holds
// global chunk (cp-row)&7; read col[ks] = (ks*4+quad+ln)&7 (row&7==ln&7).
__global__ __launch_bounds__(256, 4) void attn(const uint16_t* __restrict__ Qb,
                                               const uint16_t* __restrict__ Kb,
                                               const uint16_t* __restrict__ Vtb,
                                               uint16_t* __restrict__ Ctx) {
  __shared__ __attribute__((aligned(16))) uint16_t Ks[64 * 64];          // [t][e], chunk XOR-swizzled
  __shared__ __attribute__((aligned(16))) uint16_t Vs[64 * 64];          // [e][t], chunk XOR-swizzled
  __shared__ __attribute__((aligned(16))) uint16_t Ps[4 * 2 * 16 * 72];  // [wave][sub][q=16][t stride 72]
  const int tid = threadIdx.x;
  const int w = tid >> 6, l = tid & 63;
  const int ln = l & 15, quad = l >> 4;
  // XCD swizzle: each XCD gets 8 whole (b,h) pairs (4MB K+V = one L2).
  const int lin = blockIdx.x + (blockIdx.y << 4);  // 0..1023
  const int slot = lin >> 3;                       // 0..127 within XCD
  const int bh = (lin & 7) * 8 + (slot >> 4);      // 8 bh per XCD
  const int q0 = (slot & 15) * 128;                // 16 q-blocks per bh
  const int b = bh >> 4, h = bh & 15;
  const uint16_t* Qh = Qb + (size_t)bh * 131072;
  const uint16_t* Kh = Kb + (size_t)bh * 131072;
  const uint16_t* Vth = Vtb + (size_t)bh * 131072;

  short8 qf[2][2];
#pragma unroll
  for (int sub = 0; sub < 2; ++sub)
#pragma unroll
    for (int ks = 0; ks < 2; ++ks)
      qf[sub][ks] = *(const short8*)(Qh + (size_t)(q0 + w * 32 + sub * 16 + ln) * 64 + ks * 32 + quad * 8);

  short8 ones;
#pragma unroll
  for (int j = 0; j < 8; ++j) ones[j] = (short)0x3F80;  // bf16 1.0

  int col[2];
#pragma unroll
  for (int ks = 0; ks < 2; ++ks) col[ks] = (ks * 4 + quad + ln) & 7;
  uint16_t* Pw = Ps + w * 2304;  // wave's P: 2 subs x 16 q x 72

  f32x4 oacc[2][4] = {};
  f32x4 lacc[2] = {};

  for (int t0 = 0; t0 < 2048; t0 += 64) {
    __syncthreads();
#pragma unroll
    for (int c = 0; c < 2; ++c) {
      const int f = w * 128 + c * 64 + l;  // 512 chunks per 64x64 tile
      const int t = f >> 3, g = ((f & 7) - t) & 7;
      gld16(Kh + (size_t)(t0 + t) * 64 + g * 8, Ks + (w * 128 + c * 64) * 8);
      gld16(Vth + (size_t)t * 2048 + t0 + g * 8, Vs + (w * 128 + c * 64) * 8);
    }
    __syncthreads();

    // S^T = K Q^T: D[row=t=quad*4+i][col=q=ln]. kf shared across both subtiles.
    f32x4 sacc[2][4] = {};
    __builtin_amdgcn_s_setprio(1);
#pragma unroll
    for (int nt = 0; nt < 4; ++nt) {
      const int t = nt * 16 + ln;
#pragma unroll
      for (int ks = 0; ks < 2; ++ks) {
        const short8 kf = *(const short8*)(Ks + (t * 8 + col[ks]) * 8);
        sacc[0][nt] = __builtin_amdgcn_mfma_f32_16x16x32_bf16(kf, qf[0][ks], sacc[0][nt], 0, 0, 0);
        sacc[1][nt] = __builtin_amdgcn_mfma_f32_16x16x32_bf16(kf, qf[1][ks], sacc[1][nt], 0, 0, 0);
      }
    }
    __builtin_amdgcn_s_setprio(0);

    // P = exp2(S): lane has 4 consecutive t for q=ln -> RNE pack -> one b64 store.
#pragma unroll
    for (int sub = 0; sub < 2; ++sub)
#pragma unroll
      for (int nt = 0; nt < 4; ++nt) {
        const uint32_t u0 = __builtin_bit_cast(uint32_t, EXP2F(sacc[sub][nt][0]));
        const uint32_t u1 = __builtin_bit_cast(uint32_t, EXP2F(sacc[sub][nt][1]));
        const uint32_t u2 = __builtin_bit_cast(uint32_t, EXP2F(sacc[sub][nt][2]));
        const uint32_t u3 = __builtin_bit_cast(uint32_t, EXP2F(sacc[sub][nt][3]));
        uint2 dd;
        dd.x = ((u0 + 0x7FFFu + ((u0 >> 16) & 1u)) >> 16) |
               ((u1 + 0x7FFFu + ((u1 >> 16) & 1u)) & 0xFFFF0000u);
        dd.y = ((u2 + 0x7FFFu + ((u2 >> 16) & 1u)) >> 16) |
               ((u3 + 0x7FFFu + ((u3 >> 16) & 1u)) & 0xFFFF0000u);
        *(uint2*)(Pw + sub * 1152 + ln * 72 + nt * 16 + quad * 4) = dd;
      }

    // O += P V; rowsum via P @ ones. vf shared across subtiles.
#pragma unroll
    for (int ks = 0; ks < 2; ++ks) {
      const short8 pf0 = *(const short8*)(Pw + ln * 72 + ks * 32 + quad * 8);
      const short8 pf1 = *(const short8*)(Pw + 1152 + ln * 72 + ks * 32 + quad * 8);
      __builtin_amdgcn_s_setprio(1);
      lacc[0] = __builtin_amdgcn_mfma_f32_16x16x32_bf16(pf0, ones, lacc[0], 0, 0, 0);
      lacc[1] = __builtin_amdgcn_mfma_f32_16x16x32_bf16(pf1, ones, lacc[1], 0, 0, 0);
#pragma unroll
      for (int nt = 0; nt < 4; ++nt) {
        const int e = nt * 16 + ln;
        const short8 vf = *(const short8*)(Vs + (e * 8 + col[ks]) * 8);
        oacc[0][nt] = __builtin_amdgcn_mfma_f32_16x16x32_bf16(pf0, vf, oacc[0][nt], 0, 0, 0);
        oacc[1][nt] = __builtin_amdgcn_mfma_f32_16x16x32_bf16(pf1, vf, oacc[1][nt], 0, 0, 0);
      }
      __builtin_amdgcn_s_setprio(0);
    }
  }

#pragma unroll
  for (int sub = 0; sub < 2; ++sub) {
    float inv[4];
#pragma unroll
    for (int i = 0; i < 4; ++i) inv[i] = RCPF(lacc[sub][i]);
#pragma unroll
    for (int nt = 0; nt < 4; ++nt)
#pragma unroll
      for (int i = 0; i < 4; ++i) {
        const float v = oacc[sub][nt][i] * inv[i];
        const int s = q0 + w * 32 + sub * 16 + quad * 4 + i;
        Ctx[(size_t)(b * 2048 + s) * 1024 + h * 64 + nt * 16 + ln] = f2bf(v);
      }
  }
}

extern "C" void kernel_launch(void* const* d_in, const int* in_sizes, int n_in,
                              void* d_out, int out_size, void* d_ws, size_t ws_size,
                              hipStream_t stream) {
  const float* q = (const float*)d_in[0];
  const float* k = (const float*)d_in[1];
  const float* v = (const float*)d_in[2];
  const float* wq = (const float*)d_in[3];
  const float* bq = (const float*)d_in[4];
  const float* wk = (const float*)d_in[5];
  const float* bk = (const float*)d_in[6];
  const float* wv = (const float*)d_in[7];
  const float* bv = (const float*)d_in[8];
  const float* wo = (const float*)d_in[9];
  const float* bo = (const float*)d_in[10];
  float* out = (float*)d_out;

  uint16_t* ws = (uint16_t*)d_ws;
  uint16_t* Xq = ws;                   // 8388608 elems each (X)
  uint16_t* Xk = Xq + 8388608;
  uint16_t* Xv = Xk + 8388608;
  uint16_t* Wq = Xv + 8388608;         // 1048576 each
  uint16_t* Wk = Wq + 1048576;
  uint16_t* Wv = Wk + 1048576;
  uint16_t* Wo = Wv + 1048576;
  uint16_t* Qb = Wo + 1048576;         // 8388608
  uint16_t* Kb = Qb + 8388608;         // 8388608
  uint16_t* Ctx = Xq;                  // alias: Xq dead after QKV dispatch completes

  // Fused QKV needs Vtb disjoint from all X (z=1 reads Xk while z=2 writes).
  const size_t fused_elems = 46137344u + 8388608u;  // ~109 MB
  const bool fused = ws_size >= fused_elems * sizeof(uint16_t);
  uint16_t* Vtb = fused ? (Kb + 8388608) : Xk;  // fallback: sequential + alias (safe)

  cast3<<<dim3(8192, 3), 256, 0, stream>>>(q, k, v, Xq, Xk, Xv, 2097152);
  cast4<<<dim3(1024, 4), 256, 0, stream>>>(wq, wk, wv, wo, Wq, Wk, Wv, Wo, 262144);

  const float qscale = 0.125f * 1.4426950408889634f;  // 0.125*log2(e)
  if (fused) {
    gemm_qkv<<<dim3(8, 64, 3), 256, 0, stream>>>(Xq, Xk, Xv, Wq, Wk, Wv, bq, bk, bv,
                                                 Qb, Kb, Vtb, qscale, 0);
  } else {
    gemm_qkv<<<dim3(8, 64, 1), 256, 0, stream>>>(Xq, Xk, Xv, Wq, Wk, Wv, bq, bk, bv,
                                                 Qb, Kb, Vtb, qscale, 0);
    gemm_qkv<<<dim3(8, 64, 1), 256, 0, stream>>>(Xq, Xk, Xv, Wq, Wk, Wv, bq, bk, bv,
                                                 Qb, Kb, Vtb, qscale, 1);
    gemm_qkv<<<dim3(8, 64, 1), 256, 0, stream>>>(Xq, Xk, Xv, Wq, Wk, Wv, bq, bk, bv,
                                                 Qb, Kb, Vtb, qscale, 2);
  }

  attn<<<dim3(16, 64), 256, 0, stream>>>(Qb, Kb, Vtb, Ctx);

  gemm_out<<<dim3(8, 64), 256, 0, stream>>>(Ctx, Wo, bo, out);
}

// Round 10
// 346.980 us; speedup vs baseline: 1.0689x; 1.0689x over previous
//
#include <hip/hip_runtime.h>
#include <stdint.h>
#include <stddef.h>

// MultiHeadAttention B=4 S=2048 D=1024 H=16 E=64  (all fp32 in/out)
// R16: consolidation round (bit-identical math):
//      (1) gemm_out reverts to single-buffer 32KB core (R15's shared 64KB
//          dbuf core cost it ~2 blocks/CU; gemm_qkv keeps the dbuf core
//          which measured better there);
//      (2) cast3+cast4 fused into one castAll launch (one fewer dispatch);
//      (3) attn P-pack uses v_perm_b32 (byte-select replaces shift/and/or,
//          bit-identical RNE) -> ~20% less pack VALU (VALUBusy 49%).
// R15: gemm_qkv 2-phase dbuf w/ named buffers + full unroll. R14: BK=64 +
//      chunk-XOR swizzle (conflicts 6.29M->0), XCD remap (FETCH 49MB).
// R10: manual RNE P-pack. R9: attn swizzle col fix. R8: attn KVBLK=64.
// R7: attn XCD swizzle. R6: S^T=MFMA(kf,qf). R5: fused QKV, Vtb transposed.

typedef __attribute__((ext_vector_type(8))) short short8;
typedef __attribute__((ext_vector_type(4))) float f32x4;

#if __has_builtin(__builtin_amdgcn_exp2f)
#define EXP2F __builtin_amdgcn_exp2f
#else
#define EXP2F exp2f
#endif
#if __has_builtin(__builtin_amdgcn_rcpf)
#define RCPF __builtin_amdgcn_rcpf
#else
#define RCPF(x) (1.0f / (x))
#endif

__device__ __forceinline__ uint16_t f2bf(float f) {
  uint32_t u = __builtin_bit_cast(uint32_t, f);
  u += 0x7FFFu + ((u >> 16) & 1u);  // RNE; inputs finite
  return (uint16_t)(u >> 16);
}

// Pack the high halves of two RNE-biased u32s: (r0>>16) | (r1 & 0xFFFF0000).
__device__ __forceinline__ uint32_t pack_hi16(uint32_t r0, uint32_t r1) {
#if __has_builtin(__builtin_amdgcn_perm)
  return __builtin_amdgcn_perm(r1, r0, 0x07060302u);  // bytes r0[2],r0[3],r1[2],r1[3]
#else
  return (r0 >> 16) | (r1 & 0xFFFF0000u);
#endif
}

__device__ __forceinline__ void gld16(const void* g, void* l) {
  __builtin_amdgcn_global_load_lds((const __attribute__((address_space(1))) void*)g,
                                   (__attribute__((address_space(3))) void*)l, 16, 0, 0);
}

// Fused fp32->bf16 cast for all 7 tensors. y<3: X tensors (2097152 float4
// each). y==3: the 4 weight tensors as one 1048576-float4 range (262144 each).
__global__ __launch_bounds__(256) void castAll(const float* __restrict__ x0, const float* __restrict__ x1,
                                               const float* __restrict__ x2, const float* __restrict__ w0,
                                               const float* __restrict__ w1, const float* __restrict__ w2,
                                               const float* __restrict__ w3, uint16_t* __restrict__ dx0,
                                               uint16_t* __restrict__ dx1, uint16_t* __restrict__ dx2,
                                               uint16_t* __restrict__ dw0, uint16_t* __restrict__ dw1,
                                               uint16_t* __restrict__ dw2, uint16_t* __restrict__ dw3) {
  const int y = blockIdx.y;
  int i = blockIdx.x * 256 + threadIdx.x;
  const float* s;
  uint16_t* d;
  if (y < 3) {
    if (i >= 2097152) return;
    s = y == 0 ? x0 : (y == 1 ? x1 : x2);
    d = y == 0 ? dx0 : (y == 1 ? dx1 : dx2);
  } else {
    if (i >= 1048576) return;
    const int sub = i >> 18;  // 262144 float4 per weight tensor
    i &= 262143;
    s = sub == 0 ? w0 : (sub == 1 ? w1 : (sub == 2 ? w2 : w3));
    d = sub == 0 ? dw0 : (sub == 1 ? dw1 : (sub == 2 ? dw2 : dw3));
  }
  float4 v = ((const float4*)s)[i];
  ushort4 o;
  o.x = f2bf(v.x); o.y = f2bf(v.y); o.z = f2bf(v.z); o.w = f2bf(v.w);
  ((ushort4*)d)[i] = o;
}

// One 128x128 frag-step over the 64-wide K slice in As/Bs (chunk-XOR swizzled).
__device__ __forceinline__ void gemm_compute(const uint16_t* As, const uint16_t* Bs,
                                             f32x4 acc[4][4], int wm, int wn, int ln, int quad,
                                             const int* colk) {
#pragma unroll
  for (int kk = 0; kk < 2; ++kk) {
    short8 a[4], b[4];
#pragma unroll
    for (int mt = 0; mt < 4; ++mt)
      a[mt] = *(const short8*)(As + (wm + mt * 16 + ln) * 64 + colk[kk] * 8);
#pragma unroll
    for (int nt = 0; nt < 4; ++nt)
      b[nt] = *(const short8*)(Bs + (wn + nt * 16 + ln) * 64 + colk[kk] * 8);
#pragma unroll
    for (int mt = 0; mt < 4; ++mt)
#pragma unroll
      for (int nt = 0; nt < 4; ++nt)
        acc[mt][nt] = __builtin_amdgcn_mfma_f32_16x16x32_bf16(a[mt], b[nt], acc[mt][nt], 0, 0, 0);
  }
}

__device__ __forceinline__ void gemm_stage(const uint16_t* const* Ag, const uint16_t* const* Bg,
                                           const int* lofs, uint16_t* As, uint16_t* Bs, int k0) {
#pragma unroll
  for (int c = 0; c < 4; ++c) {
    gld16(Ag[c] + k0, As + lofs[c]);
    gld16(Bg[c] + k0, Bs + lofs[c]);
  }
}

__device__ __forceinline__ void gemm_prolog(const uint16_t* __restrict__ A,
                                            const uint16_t* __restrict__ Bw,
                                            const uint16_t** Ag, const uint16_t** Bg, int* lofs,
                                            int* colk, int m0, int n0) {
  constexpr int K = 1024;
  const int tid = threadIdx.x;
  const int l = tid & 63;
  const int ln = l & 15, quad = l >> 4;
#pragma unroll
  for (int c = 0; c < 4; ++c) {
    const int f = c * 256 + tid;              // chunk id 0..1023
    const int row = f >> 3, cp = f & 7, g = (cp - row) & 7;
    Ag[c] = A + (size_t)(m0 + row) * K + g * 8;
    Bg[c] = Bw + (size_t)(n0 + row) * K + g * 8;
    lofs[c] = f * 8;                          // linear LDS dest (elems)
  }
#pragma unroll
  for (int kk = 0; kk < 2; ++kk) colk[kk] = (kk * 4 + quad + ln) & 7;
}

// R15 2-phase core (named dbuf, full unroll) — used by gemm_qkv.
__device__ __forceinline__ void gemm_core_db(const uint16_t* __restrict__ A,
                                             const uint16_t* __restrict__ Bw,
                                             uint16_t* As0, uint16_t* Bs0,
                                             uint16_t* As1, uint16_t* Bs1,
                                             f32x4 acc[4][4], int m0, int n0) {
  const int tid = threadIdx.x;
  const int w = tid >> 6, l = tid & 63;
  const int ln = l & 15, quad = l >> 4;
  const int wm = (w >> 1) * 64, wn = (w & 1) * 64;
  const uint16_t* Ag[4];
  const uint16_t* Bg[4];
  int lofs[4], colk[2];
  gemm_prolog(A, Bw, Ag, Bg, lofs, colk, m0, n0);

  gemm_stage(Ag, Bg, lofs, As0, Bs0, 0);
  __syncthreads();
#pragma unroll
  for (int s = 0; s < 16; ++s) {
    uint16_t* Asn = (s & 1) ? As0 : As1;      // static: s is compile-time
    uint16_t* Bsn = (s & 1) ? Bs0 : Bs1;
    const uint16_t* Asc = (s & 1) ? As1 : As0;
    const uint16_t* Bsc = (s & 1) ? Bs1 : Bs0;
    if (s < 15) gemm_stage(Ag, Bg, lofs, Asn, Bsn, (s + 1) * 64);
    gemm_compute(Asc, Bsc, acc, wm, wn, ln, quad, colk);
    if (s < 15) __syncthreads();
  }
}

// R14 single-buffer core (32KB, 4 blocks/CU) — used by gemm_out.
__device__ __forceinline__ void gemm_core_sb(const uint16_t* __restrict__ A,
                                             const uint16_t* __restrict__ Bw,
                                             uint16_t* As, uint16_t* Bs,
                                             f32x4 acc[4][4], int m0, int n0) {
  const int tid = threadIdx.x;
  const int w = tid >> 6, l = tid & 63;
  const int ln = l & 15, quad = l >> 4;
  const int wm = (w >> 1) * 64, wn = (w & 1) * 64;
  const uint16_t* Ag[4];
  const uint16_t* Bg[4];
  int lofs[4], colk[2];
  gemm_prolog(A, Bw, Ag, Bg, lofs, colk, m0, n0);

  for (int k0 = 0; k0 < 1024; k0 += 64) {
    __syncthreads();
    gemm_stage(Ag, Bg, lofs, As, Bs, k0);
    __syncthreads();
    gemm_compute(As, Bs, acc, wm, wn, ln, quad, colk);
  }
}

// Fused QKV projection: z selects tensor.
// z=0: Q -> [B,H,S,E] scaled; z=1: K -> [B,H,S,E]; z=2: V -> [B,H,E,S] (transposed).
// XCD remap: xcd = lin&7 owns contiguous (z,m)-chunk x all 8 n-tiles ->
// A-tile reused 8x inside one L2 (measured: FETCH 200->49MB).
__global__ __launch_bounds__(256) void gemm_qkv(const uint16_t* __restrict__ Xq, const uint16_t* __restrict__ Xk,
                                                const uint16_t* __restrict__ Xv, const uint16_t* __restrict__ Wq,
                                                const uint16_t* __restrict__ Wk, const uint16_t* __restrict__ Wv,
                                                const float* __restrict__ bq, const float* __restrict__ bk,
                                                const float* __restrict__ bv, uint16_t* __restrict__ Qb,
                                                uint16_t* __restrict__ Kb, uint16_t* __restrict__ Vtb,
                                                float qscale, int zbase) {
  __shared__ __attribute__((aligned(16))) uint16_t As0[128 * 64];
  __shared__ __attribute__((aligned(16))) uint16_t Bs0[128 * 64];
  __shared__ __attribute__((aligned(16))) uint16_t As1[128 * 64];
  __shared__ __attribute__((aligned(16))) uint16_t Bs1[128 * 64];
  const int lin = blockIdx.x + (blockIdx.y << 3) + (blockIdx.z << 9);
  const int per = gridDim.z << 3;                // mz-tiles per XCD
  const int xcd = lin & 7, local = lin >> 3;
  const int mz = xcd * per + (local >> 3);
  const int z = (mz >> 6) + zbase;
  const int m0 = (mz & 63) * 128, n0 = (local & 7) * 128;

  const uint16_t* A = z == 0 ? Xq : (z == 1 ? Xk : Xv);
  const uint16_t* Bw = z == 0 ? Wq : (z == 1 ? Wk : Wv);
  const float* bias = z == 0 ? bq : (z == 1 ? bk : bv);
  uint16_t* Cout = z == 0 ? Qb : (z == 1 ? Kb : Vtb);
  const float scale = z == 0 ? qscale : 1.0f;

  f32x4 acc[4][4] = {};
  gemm_core_db(A, Bw, As0, Bs0, As1, Bs1, acc, m0, n0);

  const int tid = threadIdx.x;
  const int w = tid >> 6, l = tid & 63;
  const int ln = l & 15, quad = l >> 4;
  const int wm = (w >> 1) * 64, wn = (w & 1) * 64;
#pragma unroll
  for (int nt = 0; nt < 4; ++nt) {
    const int col = n0 + wn + nt * 16 + ln;
    const float bv_ = bias[col];
    const int h = col >> 6, e = col & 63;
#pragma unroll
    for (int mt = 0; mt < 4; ++mt) {
#pragma unroll
      for (int i = 0; i < 4; ++i) {
        const int row = m0 + wm + mt * 16 + quad * 4 + i;
        const int b_ = row >> 11, s = row & 2047;
        const float v = (acc[mt][nt][i] + bv_) * scale;
        if (z != 2) {
          Cout[(size_t)(b_ * 16 + h) * 131072 + s * 64 + e] = f2bf(v);
        } else {
          Cout[(size_t)(b_ * 16 + h) * 131072 + e * 2048 + s] = f2bf(v);
        }
      }
    }
  }
}

// Output projection: fp32 row-major out. Same XCD remap (per=8). Single-buf core.
__global__ __launch_bounds__(256) void gemm_out(const uint16_t* __restrict__ A, const uint16_t* __restrict__ Bw,
                                                const float* __restrict__ bias, float* __restrict__ Cout) {
  __shared__ __attribute__((aligned(16))) uint16_t As[128 * 64];
  __shared__ __attribute__((aligned(16))) uint16_t Bs[128 * 64];
  const int lin = blockIdx.x + (blockIdx.y << 3);
  const int xcd = lin & 7, local = lin >> 3;
  const int m0 = (xcd * 8 + (local >> 3)) * 128, n0 = (local & 7) * 128;
  f32x4 acc[4][4] = {};
  gemm_core_sb(A, Bw, As, Bs, acc, m0, n0);

  const int tid = threadIdx.x;
  const int w = tid >> 6, l = tid & 63;
  const int ln = l & 15, quad = l >> 4;
  const int wm = (w >> 1) * 64, wn = (w & 1) * 64;
#pragma unroll
  for (int nt = 0; nt < 4; ++nt) {
    const int col = n0 + wn + nt * 16 + ln;
    const float bv_ = bias[col];
#pragma unroll
    for (int mt = 0; mt < 4; ++mt)
#pragma unroll
      for (int i = 0; i < 4; ++i) {
        const int row = m0 + wm + mt * 16 + quad * 4 + i;
        Cout[(size_t)row * 1024 + col] = acc[mt][nt][i] + bv_;
      }
  }
}

// One block = 128 query rows of one (b,h); wave = 32 rows (2 subtiles of 16).
// R10 attn structure: KVBLK=64 -> LDS 34.8KB -> 4 blocks/CU. K/V staged via
// global_load_lds with chunk XOR-swizzle: LDS[row][cp] holds global chunk
// (cp-row)&7; read col[ks] = (ks*4+quad+ln)&7 (row&7==ln&7).
// R16: P-pack via v_perm_b32 (bit-identical RNE, fewer VALU ops).
__global__ __launch_bounds__(256, 4) void attn(const uint16_t* __restrict__ Qb,
                                               const uint16_t* __restrict__ Kb,
                                               const uint16_t* __restrict__ Vtb,
                                               uint16_t* __restrict__ Ctx) {
  __shared__ __attribute__((aligned(16))) uint16_t Ks[64 * 64];          // [t][e], chunk XOR-swizzled
  __shared__ __attribute__((aligned(16))) uint16_t Vs[64 * 64];          // [e][t], chunk XOR-swizzled
  __shared__ __attribute__((aligned(16))) uint16_t Ps[4 * 2 * 16 * 72];  // [wave][sub][q=16][t stride 72]
  const int tid = threadIdx.x;
  const int w = tid >> 6, l = tid & 63;
  const int ln = l & 15, quad = l >> 4;
  // XCD swizzle: each XCD gets 8 whole (b,h) pairs (4MB K+V = one L2).
  const int lin = blockIdx.x + (blockIdx.y << 4);  // 0..1023
  const int slot = lin >> 3;                       // 0..127 within XCD
  const int bh = (lin & 7) * 8 + (slot >> 4);      // 8 bh per XCD
  const int q0 = (slot & 15) * 128;                // 16 q-blocks per bh
  const int b = bh >> 4, h = bh & 15;
  const uint16_t* Qh = Qb + (size_t)bh * 131072;
  const uint16_t* Kh = Kb + (size_t)bh * 131072;
  const uint16_t* Vth = Vtb + (size_t)bh * 131072;

  short8 qf[2][2];
#pragma unroll
  for (int sub = 0; sub < 2; ++sub)
#pragma unroll
    for (int ks = 0; ks < 2; ++ks)
      qf[sub][ks] = *(const short8*)(Qh + (size_t)(q0 + w * 32 + sub * 16 + ln) * 64 + ks * 32 + quad * 8);

  short8 ones;
#pragma unroll
  for (int j = 0; j < 8; ++j) ones[j] = (short)0x3F80;  // bf16 1.0

  int col[2];
#pragma unroll
  for (int ks = 0; ks < 2; ++ks) col[ks] = (ks * 4 + quad + ln) & 7;
  uint16_t* Pw = Ps + w * 2304;  // wave's P: 2 subs x 16 q x 72

  f32x4 oacc[2][4] = {};
  f32x4 lacc[2] = {};

  for (int t0 = 0; t0 < 2048; t0 += 64) {
    __syncthreads();
#pragma unroll
    for (int c = 0; c < 2; ++c) {
      const int f = w * 128 + c * 64 + l;  // 512 chunks per 64x64 tile
      const int t = f >> 3, g = ((f & 7) - t) & 7;
      gld16(Kh + (size_t)(t0 + t) * 64 + g * 8, Ks + (w * 128 + c * 64) * 8);
      gld16(Vth + (size_t)t * 2048 + t0 + g * 8, Vs + (w * 128 + c * 64) * 8);
    }
    __syncthreads();

    // S^T = K Q^T: D[row=t=quad*4+i][col=q=ln]. kf shared across both subtiles.
    f32x4 sacc[2][4] = {};
    __builtin_amdgcn_s_setprio(1);
#pragma unroll
    for (int nt = 0; nt < 4; ++nt) {
      const int t = nt * 16 + ln;
#pragma unroll
      for (int ks = 0; ks < 2; ++ks) {
        const short8 kf = *(const short8*)(Ks + (t * 8 + col[ks]) * 8);
        sacc[0][nt] = __builtin_amdgcn_mfma_f32_16x16x32_bf16(kf, qf[0][ks], sacc[0][nt], 0, 0, 0);
        sacc[1][nt] = __builtin_amdgcn_mfma_f32_16x16x32_bf16(kf, qf[1][ks], sacc[1][nt], 0, 0, 0);
      }
    }
    __builtin_amdgcn_s_setprio(0);

    // P = exp2(S): lane has 4 consecutive t for q=ln -> RNE bias + v_perm pack.
#pragma unroll
    for (int sub = 0; sub < 2; ++sub)
#pragma unroll
      for (int nt = 0; nt < 4; ++nt) {
        const uint32_t u0 = __builtin_bit_cast(uint32_t, EXP2F(sacc[sub][nt][0]));
        const uint32_t u1 = __builtin_bit_cast(uint32_t, EXP2F(sacc[sub][nt][1]));
        const uint32_t u2 = __builtin_bit_cast(uint32_t, EXP2F(sacc[sub][nt][2]));
        const uint32_t u3 = __builtin_bit_cast(uint32_t, EXP2F(sacc[sub][nt][3]));
        const uint32_t r0 = u0 + 0x7FFFu + ((u0 >> 16) & 1u);
        const uint32_t r1 = u1 + 0x7FFFu + ((u1 >> 16) & 1u);
        const uint32_t r2 = u2 + 0x7FFFu + ((u2 >> 16) & 1u);
        const uint32_t r3 = u3 + 0x7FFFu + ((u3 >> 16) & 1u);
        uint2 dd;
        dd.x = pack_hi16(r0, r1);
        dd.y = pack_hi16(r2, r3);
        *(uint2*)(Pw + sub * 1152 + ln * 72 + nt * 16 + quad * 4) = dd;
      }

    // O += P V; rowsum via P @ ones. vf shared across subtiles.
#pragma unroll
    for (int ks = 0; ks < 2; ++ks) {
      const short8 pf0 = *(const short8*)(Pw + ln * 72 + ks * 32 + quad * 8);
      const short8 pf1 = *(const short8*)(Pw + 1152 + ln * 72 + ks * 32 + quad * 8);
      __builtin_amdgcn_s_setprio(1);
      lacc[0] = __builtin_amdgcn_mfma_f32_16x16x32_bf16(pf0, ones, lacc[0], 0, 0, 0);
      lacc[1] = __builtin_amdgcn_mfma_f32_16x16x32_bf16(pf1, ones, lacc[1], 0, 0, 0);
#pragma unroll
      for (int nt = 0; nt < 4; ++nt) {
        const int e = nt * 16 + ln;
        const short8 vf = *(const short8*)(Vs + (e * 8 + col[ks]) * 8);
        oacc[0][nt] = __builtin_amdgcn_mfma_f32_16x16x32_bf16(pf0, vf, oacc[0][nt], 0, 0, 0);
        oacc[1][nt] = __builtin_amdgcn_mfma_f32_16x16x32_bf16(pf1, vf, oacc[1][nt], 0, 0, 0);
      }
      __builtin_amdgcn_s_setprio(0);
    }
  }

#pragma unroll
  for (int sub = 0; sub < 2; ++sub) {
    float inv[4];
#pragma unroll
    for (int i = 0; i < 4; ++i) inv[i] = RCPF(lacc[sub][i]);
#pragma unroll
    for (int nt = 0; nt < 4; ++nt)
#pragma unroll
      for (int i = 0; i < 4; ++i) {
        const float v = oacc[sub][nt][i] * inv[i];
        const int s = q0 + w * 32 + sub * 16 + quad * 4 + i;
        Ctx[(size_t)(b * 2048 + s) * 1024 + h * 64 + nt * 16 + ln] = f2bf(v);
      }
  }
}

extern "C" void kernel_launch(void* const* d_in, const int* in_sizes, int n_in,
                              void* d_out, int out_size, void* d_ws, size_t ws_size,
                              hipStream_t stream) {
  const float* q = (const float*)d_in[0];
  const float* k = (const float*)d_in[1];
  const float* v = (const float*)d_in[2];
  const float* wq = (const float*)d_in[3];
  const float* bq = (const float*)d_in[4];
  const float* wk = (const float*)d_in[5];
  const float* bk = (const float*)d_in[6];
  const float* wv = (const float*)d_in[7];
  const float* bv = (const float*)d_in[8];
  const float* wo = (const float*)d_in[9];
  const float* bo = (const float*)d_in[10];
  float* out = (float*)d_out;

  uint16_t* ws = (uint16_t*)d_ws;
  uint16_t* Xq = ws;                   // 8388608 elems each (X)
  uint16_t* Xk = Xq + 8388608;
  uint16_t* Xv = Xk + 8388608;
  uint16_t* Wq = Xv + 8388608;         // 1048576 each
  uint16_t* Wk = Wq + 1048576;
  uint16_t* Wv = Wk + 1048576;
  uint16_t* Wo = Wv + 1048576;
  uint16_t* Qb = Wo + 1048576;         // 8388608
  uint16_t* Kb = Qb + 8388608;         // 8388608
  uint16_t* Ctx = Xq;                  // alias: Xq dead after QKV dispatch completes

  // Fused QKV needs Vtb disjoint from all X (z=1 reads Xk while z=2 writes).
  const size_t fused_elems = 46137344u + 8388608u;  // ~109 MB
  const bool fused = ws_size >= fused_elems * sizeof(uint16_t);
  uint16_t* Vtb = fused ? (Kb + 8388608) : Xk;  // fallback: sequential + alias (safe)

  castAll<<<dim3(8192, 4), 256, 0, stream>>>(q, k, v, wq, wk, wv, wo,
                                             Xq, Xk, Xv, Wq, Wk, Wv, Wo);

  const float qscale = 0.125f * 1.4426950408889634f;  // 0.125*log2(e)
  if (fused) {
    gemm_qkv<<<dim3(8, 64, 3), 256, 0, stream>>>(Xq, Xk, Xv, Wq, Wk, Wv, bq, bk, bv,
                                                 Qb, Kb, Vtb, qscale, 0);
  } else {
    gemm_qkv<<<dim3(8, 64, 1), 256, 0, stream>>>(Xq, Xk, Xv, Wq, Wk, Wv, bq, bk, bv,
                                                 Qb, Kb, Vtb, qscale, 0);
    gemm_qkv<<<dim3(8, 64, 1), 256, 0, stream>>>(Xq, Xk, Xv, Wq, Wk, Wv, bq, bk, bv,
                                                 Qb, Kb, Vtb, qscale, 1);
    gemm_qkv<<<dim3(8, 64, 1), 256, 0, stream>>>(Xq, Xk, Xv, Wq, Wk, Wv, bq, bk, bv,
                                                 Qb, Kb, Vtb, qscale, 2);
  }

  attn<<<dim3(16, 64), 256, 0, stream>>>(Qb, Kb, Vtb, Ctx);

  gemm_out<<<dim3(8, 64), 256, 0, stream>>>(Ctx, Wo, bo, out);
}